// Round 6
// baseline (493.428 us; speedup 1.0000x reference)
//
#include <hip/hip_runtime.h>

#define NN 20000
#define IC 128
#define OC 128
#define NSTEP 32
#define NE 256000
#define KSEL 128000
#define NB 79        // prefix-scan blocks = ceil(NN/256)
#define CANDCAP 131072
#define NQCOL 704    // 512 beta + 32 p + 128 V + 32 pad

struct SelState {
  unsigned long long prefix;
  unsigned r;       // remaining rank
  unsigned selc;    // selected count
  unsigned tiec;    // candidate count
  unsigned done[8]; // block-done counters
};

typedef __attribute__((ext_vector_type(16))) float f16v;

// ---------------------------------------------------------------- init / fold
// Wq layout: float4 index = k4*NQCOL + col ; element jj = W[col][4*k4+jj]
// k4=0..31 weights; k4==32 = bias row (elements jj>0 are 0); cols 672..703 = 0
__global__ void k_init(const float* __restrict__ p_t, const float* __restrict__ lin_w,
                       const float* __restrict__ inc_w, const float* __restrict__ inc_b,
                       float* __restrict__ Wq,
                       double* __restrict__ Ud, double* __restrict__ ubd,
                       unsigned* __restrict__ cnt, unsigned* __restrict__ hist,
                       SelState* st) {
  int i = blockIdx.x * blockDim.x + threadIdx.x;
  if (i < 33 * NQCOL) {
    int k4 = i / NQCOL, col = i - k4 * NQCOL;
    float4 o;
    float* ov = (float*)&o;
    for (int jj = 0; jj < 4; ++jj) {
      int k = 4 * k4 + jj;
      float v = 0.f;
      if (col < 512) {
        int t = col >> 4, c = col & 15;
        if (k < 128) v = inc_w[k * 1024 + t * 32 + c];
        else if (k == 128) v = inc_b[t * 32 + c];
      } else if (col < 544) {
        int t = col - 512;
        if (k < 128) {
          float a = 0.f;
          for (int q = 0; q < 16; ++q) a += inc_w[k * 1024 + t * 32 + 16 + q] * p_t[t * 16 + q];
          v = a;
        } else if (k == 128) {
          float a = 0.f;
          for (int q = 0; q < 16; ++q) a += inc_b[t * 32 + 16 + q] * p_t[t * 16 + q];
          v = a;
        }
      } else if (col < 672) {
        int c = col - 544;
        if (k < 128) v = lin_w[k * OC + c];
        // k==128 (bias) patched by k_init2
      }
      ov[jj] = v;
    }
    ((float4*)Wq)[i] = o;
    return;
  }
  i -= 33 * NQCOL;
  if (i < 17 * IC) {  // f64 folded selection columns: U (16) and q (1)
    int c = i >> 7, k = i & 127;
    double a = 0.0;
    if (c < 16) {
      for (int t = 0; t < NSTEP; ++t) a += (double)inc_w[k * 1024 + t * 32 + c];
    } else {
      for (int t = 0; t < NSTEP; ++t)
        for (int q = 0; q < 16; ++q)
          a += (double)inc_w[k * 1024 + t * 32 + 16 + q] * (double)p_t[t * 16 + q];
    }
    Ud[c * IC + k] = a;
    return;
  }
  i -= 17 * IC;
  if (i < 17) {
    double a = 0.0;
    if (i < 16) {
      for (int t = 0; t < NSTEP; ++t) a += (double)inc_b[t * 32 + i];
    } else {
      for (int t = 0; t < NSTEP; ++t)
        for (int q = 0; q < 16; ++q)
          a += (double)inc_b[t * 32 + 16 + q] * (double)p_t[t * 16 + q];
    }
    ubd[i] = a;
    return;
  }
  i -= 17;
  if (i < NN) { cnt[i] = 0u; return; }
  i -= NN;
  if (i < 512) { hist[i] = 0u; return; }
  i -= 512;
  if (i == 0) {
    st->prefix = 0ull; st->r = KSEL; st->selc = 0u; st->tiec = 0u;
    for (int p = 0; p < 8; ++p) st->done[p] = 0u;
  }
}

// patch: bias row for V columns (k==128 -> k4==32, element 0)
__global__ void k_init2(const float* __restrict__ lin_b, float* __restrict__ Wq) {
  int c = threadIdx.x;  // 0..127
  Wq[((size_t)32 * NQCOL + 544 + c) * 4 + 0] = lin_b[c];
}

// ---------------- per-node GEMM: uniform weights, per-lane node rows
// grid = nodegroups x 4 splits; block = 4 waves; work in wave-level units:
//   units 0..31  : beta timestep t (16 w_v cols + 1 p col, finalized in-reg)
//   units 32..39 : V column group (16 cols)
//   unit  40     : f64 selection scalar s64 (in-register)
#define FMA4(WV, BASE)                                                                        \
  acc[BASE+0] = fmaf(xf.x, WV[0],  fmaf(xf.y, WV[1],  fmaf(xf.z, WV[2],  fmaf(xf.w, WV[3],  acc[BASE+0])))); \
  acc[BASE+1] = fmaf(xf.x, WV[4],  fmaf(xf.y, WV[5],  fmaf(xf.z, WV[6],  fmaf(xf.w, WV[7],  acc[BASE+1])))); \
  acc[BASE+2] = fmaf(xf.x, WV[8],  fmaf(xf.y, WV[9],  fmaf(xf.z, WV[10], fmaf(xf.w, WV[11], acc[BASE+2])))); \
  acc[BASE+3] = fmaf(xf.x, WV[12], fmaf(xf.y, WV[13], fmaf(xf.z, WV[14], fmaf(xf.w, WV[15], acc[BASE+3]))));

__global__ __launch_bounds__(256) void k_node(
    const float* __restrict__ x, const float* __restrict__ mw,
    const float* __restrict__ Wq, const double* __restrict__ Ud,
    const double* __restrict__ ubd,
    float* __restrict__ beta, double* __restrict__ s64, float* __restrict__ V) {
  __shared__ float4 xl[64 * 32];       // rotated: [m*32 + ((k4+m)&31)]
  int tid = threadIdx.x;
  int g = blockIdx.x >> 2;             // node group
  int s = blockIdx.x & 3;              // split
  int n0 = g * 64;
  int nvalid = NN - n0; if (nvalid > 64) nvalid = 64;

  for (int i = tid; i < 64 * 32; i += 256) {
    int mm = i >> 5, k4 = i & 31;
    float4 v = make_float4(0.f, 0.f, 0.f, 0.f);
    if (mm < nvalid) v = ((const float4*)(x + (size_t)(n0 + mm) * IC))[k4];
    xl[(mm << 5) + ((k4 + mm) & 31)] = v;
  }

  int m = tid & 63;
  int j = __builtin_amdgcn_readfirstlane(threadIdx.x >> 6);  // wave id 0..3
  float mwr[16];
  {
    int mm = (m < nvalid) ? m : 0;
    const float4* mp = (const float4*)(mw + (size_t)(n0 + mm) * 16);
#pragma unroll
    for (int i = 0; i < 4; ++i) {
      float4 t4 = mp[i];
      mwr[4 * i] = t4.x; mwr[4 * i + 1] = t4.y; mwr[4 * i + 2] = t4.z; mwr[4 * i + 3] = t4.w;
    }
  }
  __syncthreads();

  int base = (s == 0) ? 0 : (s == 1) ? 11 : (s == 2) ? 22 : 32;
  int cnt  = (s == 0) ? 11 : (s == 1) ? 11 : (s == 2) ? 10 : 9;

  for (int i = j; i < cnt; i += 4) {
    int u = base + i;
    if (u < 32) {                       // ---- beta unit, timestep t = u
      int t = u;
      const f16v*   wb = (const f16v*)Wq + (t << 2);      // cols t*16..t*16+15
      const float4* wp = (const float4*)Wq + (512 + t);   // p-col
      float acc[16], accp;
      {
        const f16v* wkb = wb + 32 * 176;
        f16v b0 = wkb[0], b1 = wkb[1], b2 = wkb[2], b3 = wkb[3];
#pragma unroll
        for (int c = 0; c < 4; ++c) {
          acc[c] = b0[4 * c]; acc[4 + c] = b1[4 * c];
          acc[8 + c] = b2[4 * c]; acc[12 + c] = b3[4 * c];
        }
        accp = wp[32 * NQCOL].x;
      }
      for (int k4 = 0; k4 < 32; ++k4) {
        float4 xf = xl[(m << 5) + ((k4 + m) & 31)];
        const f16v* wk = wb + k4 * 176;
        f16v w0 = wk[0], w1 = wk[1], w2 = wk[2], w3 = wk[3];
        float4 pw = wp[k4 * NQCOL];
        FMA4(w0, 0) FMA4(w1, 4) FMA4(w2, 8) FMA4(w3, 12)
        accp = fmaf(xf.x, pw.x, fmaf(xf.y, pw.y, fmaf(xf.z, pw.z, fmaf(xf.w, pw.w, accp))));
      }
      float bs = accp;
#pragma unroll
      for (int c = 0; c < 16; ++c) bs = fmaf(acc[c], mwr[c], bs);
      if (m < nvalid) beta[(size_t)(n0 + m) * NSTEP + t] = bs * (1.f / 32.f);
    } else if (u < 40) {                // ---- V unit, cols vc0..vc0+15
      int vc0 = (u - 32) << 4;
      const f16v* wb = (const f16v*)Wq + 136 + ((u - 32) << 2);
      float acc[16];
      {
        const f16v* wkb = wb + 32 * 176;
        f16v b0 = wkb[0], b1 = wkb[1], b2 = wkb[2], b3 = wkb[3];
#pragma unroll
        for (int c = 0; c < 4; ++c) {
          acc[c] = b0[4 * c]; acc[4 + c] = b1[4 * c];
          acc[8 + c] = b2[4 * c]; acc[12 + c] = b3[4 * c];
        }
      }
      for (int k4 = 0; k4 < 32; ++k4) {
        float4 xf = xl[(m << 5) + ((k4 + m) & 31)];
        const f16v* wk = wb + k4 * 176;
        f16v w0 = wk[0], w1 = wk[1], w2 = wk[2], w3 = wk[3];
        FMA4(w0, 0) FMA4(w1, 4) FMA4(w2, 8) FMA4(w3, 12)
      }
      if (m < nvalid) {
        float* vout = V + (size_t)(n0 + m) * OC + vc0;
#pragma unroll
        for (int q = 0; q < 4; ++q) {
          float4 o;
          o.x = fmaxf(acc[4 * q], 0.f);     o.y = fmaxf(acc[4 * q + 1], 0.f);
          o.z = fmaxf(acc[4 * q + 2], 0.f); o.w = fmaxf(acc[4 * q + 3], 0.f);
          ((float4*)vout)[q] = o;
        }
      }
    } else {                            // ---- f64 selection unit
      double dots[17];
#pragma unroll
      for (int c = 0; c < 17; ++c) {
        const double* uc = Ud + c * IC;
        double a = 0.0;
        for (int k4 = 0; k4 < 32; ++k4) {
          float4 xv = xl[(m << 5) + ((k4 + m) & 31)];
          a = fma((double)xv.x, uc[4 * k4], a);
          a = fma((double)xv.y, uc[4 * k4 + 1], a);
          a = fma((double)xv.z, uc[4 * k4 + 2], a);
          a = fma((double)xv.w, uc[4 * k4 + 3], a);
        }
        dots[c] = a;
      }
      double ssum = dots[16] + ubd[16];
#pragma unroll
      for (int c = 0; c < 16; ++c) ssum += (dots[c] + ubd[c]) * (double)mwr[c];
      if (m < nvalid) s64[n0 + m] = ssum * (1.0 / 1024.0);
    }
  }
}

// ---------------------------------------------------------------- edge keys
__global__ void k_key(const int* __restrict__ ei, const float* __restrict__ ew,
                      const double* __restrict__ s64, unsigned long long* __restrict__ keys) {
  int e = blockIdx.x * 256 + threadIdx.x;
  if (e >= NE) return;
  int d = ei[NE + e];
  double v = s64[d] * (double)ew[e];
  unsigned long long u = (unsigned long long)__double_as_longlong(v);
  u = (u & 0x8000000000000000ull) ? ~u : (u | 0x8000000000000000ull);
  keys[e] = u;
}

// ------------------- radix select pass (hist + parallel suffix-scan pick)
__global__ void k_radix(const unsigned long long* __restrict__ keys,
                        unsigned* __restrict__ hist, SelState* st, int p) {
  __shared__ unsigned h[256], suf[256];
  __shared__ int last;
  int tid = threadIdx.x;
  h[tid] = 0u;
  if (tid == 0) last = 0;
  unsigned long long pref = (p == 0) ? 0ull : st->prefix;
  __syncthreads();
  int shift = 56 - 8 * p;
  unsigned* hp = hist + p * 256;
  for (int e = blockIdx.x * 256 + tid; e < NE; e += gridDim.x * 256) {
    unsigned long long k = keys[e];
    if (p == 0 || (k >> (shift + 8)) == pref)
      atomicAdd(&h[(unsigned)((k >> shift) & 255ull)], 1u);
  }
  __syncthreads();
  if (h[tid]) atomicAdd(&hp[tid], h[tid]);
  __threadfence();
  __syncthreads();
  if (tid == 0) {
    unsigned old = atomicAdd(&st->done[p], 1u);
    if (old == gridDim.x - 1) last = 1;
  }
  __syncthreads();
  if (!last) return;
  unsigned c = atomicAdd(&hp[tid], 0u);
  suf[tid] = c;
  __syncthreads();
  for (int d = 1; d < 256; d <<= 1) {
    unsigned v = (tid + d < 256) ? suf[tid + d] : 0u;
    __syncthreads();
    suf[tid] += v;
    __syncthreads();
  }
  unsigned r = st->r;
  unsigned exc = suf[tid] - c;
  if (exc < r && exc + c >= r) {
    st->prefix = (st->prefix << 8) | (unsigned long long)tid;
    st->r = r - exc;
  }
}

// ------------------- collect candidates matching the 16-bit prefix
__global__ void k_cand(const unsigned long long* __restrict__ keys, SelState* st,
                       unsigned long long* __restrict__ candk, int* __restrict__ cande) {
  int e = blockIdx.x * 256 + threadIdx.x;
  if (e >= NE) return;
  unsigned long long k = keys[e];
  if ((unsigned)(k >> 48) == (unsigned)st->prefix) {
    unsigned pos = atomicAdd(&st->tiec, 1u);
    if (pos < CANDCAP) { candk[pos] = k; cande[pos] = e; }
  }
}

// ----------- single block: resolve bytes 2..7 over candidates + tie select
__global__ void k_sel(const unsigned long long* __restrict__ candk,
                      const int* __restrict__ cande, const int* __restrict__ ei,
                      SelState* st, int* __restrict__ sel, unsigned* __restrict__ cnt) {
  __shared__ unsigned h[256], suf[256];
  __shared__ unsigned long long spref;
  __shared__ unsigned sr;
  int tid = threadIdx.x;
  unsigned C = st->tiec; if (C > CANDCAP) C = CANDCAP;
  if (tid == 0) { spref = st->prefix; sr = st->r; }
  __syncthreads();
  for (int p = 2; p < 8; ++p) {
    h[tid] = 0u;
    __syncthreads();
    int shift = 56 - 8 * p;
    unsigned long long pf = spref;
    unsigned r = sr;
    for (unsigned i = tid; i < C; i += 256) {
      unsigned long long k = candk[i];
      if ((k >> (shift + 8)) == pf) atomicAdd(&h[(unsigned)((k >> shift) & 255ull)], 1u);
    }
    __syncthreads();
    suf[tid] = h[tid];
    __syncthreads();
    for (int d = 1; d < 256; d <<= 1) {
      unsigned v = (tid + d < 256) ? suf[tid + d] : 0u;
      __syncthreads();
      suf[tid] += v;
      __syncthreads();
    }
    unsigned exc = suf[tid] - h[tid];
    if (exc < r && exc + h[tid] >= r) {
      spref = (pf << 8) | (unsigned long long)tid;
      sr = r - exc;
    }
    __syncthreads();
  }
  unsigned long long T = spref;
  unsigned needed = sr;
  if (tid == 0) { st->prefix = T; st->r = needed; }
  // ties: take lowest-index `needed` among keys == T
  for (unsigned i = tid; i < C; i += 256) {
    if (candk[i] == T) {
      int e = cande[i];
      unsigned rank = 0;
      for (unsigned q = 0; q < C; ++q)
        rank += (candk[q] == T && cande[q] < e) ? 1u : 0u;
      if (rank < needed) {
        unsigned pos = atomicAdd(&st->selc, 1u);
        if (pos < KSEL) { sel[pos] = e; atomicAdd(&cnt[ei[e]], 1u); }
      }
    }
  }
}

// --------------------------------------------------- selection (> T) + counts
__global__ void k_compact(const unsigned long long* __restrict__ keys,
                          const int* __restrict__ ei, SelState* st,
                          int* __restrict__ sel, unsigned* __restrict__ cnt) {
  int e = blockIdx.x * 256 + threadIdx.x;
  if (e >= NE) return;
  if (keys[e] > st->prefix) {
    unsigned pos = atomicAdd(&st->selc, 1u);
    if (pos < KSEL) { sel[pos] = e; atomicAdd(&cnt[ei[e]], 1u); }
  }
}

// ----------------------------------------------- 3-phase prefix sum -> CSR
__global__ void k_pref1(const unsigned* __restrict__ cnt, unsigned* __restrict__ bsum) {
  __shared__ unsigned sd[256];
  int i = blockIdx.x * 256 + threadIdx.x;
  sd[threadIdx.x] = (i < NN) ? cnt[i] : 0u;
  __syncthreads();
  for (int s = 128; s > 0; s >>= 1) {
    if (threadIdx.x < s) sd[threadIdx.x] += sd[threadIdx.x + s];
    __syncthreads();
  }
  if (threadIdx.x == 0) bsum[blockIdx.x] = sd[0];
}

__global__ void k_pref2(const unsigned* __restrict__ bsum, unsigned* __restrict__ bbase,
                        unsigned* __restrict__ offar) {
  __shared__ unsigned sd[128];
  int tid = threadIdx.x;
  unsigned v = (tid < NB) ? bsum[tid] : 0u;
  sd[tid] = v;
  __syncthreads();
  for (int d = 1; d < 128; d <<= 1) {
    unsigned u = (tid >= d) ? sd[tid - d] : 0u;
    __syncthreads();
    sd[tid] += u;
    __syncthreads();
  }
  if (tid < NB) bbase[tid] = sd[tid] - v;
  if (tid == NB - 1) offar[NN] = sd[tid];
}

__global__ void k_pref3(const unsigned* __restrict__ cnt, const unsigned* __restrict__ bbase,
                        unsigned* __restrict__ offar, unsigned* __restrict__ cursor) {
  __shared__ unsigned sd[256];
  int tid = threadIdx.x;
  int i = blockIdx.x * 256 + tid;
  unsigned v = (i < NN) ? cnt[i] : 0u;
  sd[tid] = v;
  __syncthreads();
  for (int d = 1; d < 256; d <<= 1) {
    unsigned u = (tid >= d) ? sd[tid - d] : 0u;
    __syncthreads();
    sd[tid] += u;
    __syncthreads();
  }
  if (i < NN) {
    unsigned excl = bbase[blockIdx.x] + sd[tid] - v;
    offar[i] = excl;
    cursor[i] = excl;
  }
}

__global__ void k_scatter(const int* __restrict__ sel, const int* __restrict__ ei,
                          unsigned* __restrict__ cursor, int* __restrict__ csr) {
  int i = blockIdx.x * 256 + threadIdx.x;
  if (i >= KSEL) return;
  int e = sel[i];
  unsigned pos = atomicAdd(&cursor[ei[e]], 1u);
  if (pos < KSEL) csr[pos] = e;
}

// ------------------------------------- per-node softmax + weighted scatter
__global__ __launch_bounds__(128) void k_out(
    const int* __restrict__ ei, const float* __restrict__ ew,
    const float* __restrict__ beta, const float* __restrict__ V,
    const unsigned* __restrict__ offar, const int* __restrict__ csr,
    float* __restrict__ out) {
  __shared__ float m[NSTEP], den[NSTEP];
  __shared__ float g[32][NSTEP];
  __shared__ int dl[32];
  __shared__ float ewl[32];
  int n = blockIdx.x, tid = threadIdx.x;
  unsigned beg = offar[n], end = offar[n + 1];
  if (end > (unsigned)KSEL) end = KSEL;
  if (beg > end) beg = end;
  if (tid < NSTEP) {
    float mm = -INFINITY;
    for (unsigned i = beg; i < end; ++i) {
      int e = csr[i]; int d = ei[NE + e];
      float v = beta[d * NSTEP + tid] * ew[e];
      mm = fmaxf(mm, v);
    }
    m[tid] = mm;
    float dd = 0.f;
    for (unsigned i = beg; i < end; ++i) {
      int e = csr[i]; int d = ei[NE + e];
      float v = beta[d * NSTEP + tid] * ew[e];
      dd += expf(v - mm);
    }
    den[tid] = dd;
  }
  __syncthreads();
  float acc = 0.f;
  int c = tid, tq = tid >> 2;
  for (unsigned cb = beg; cb < end; cb += 32u) {
    unsigned ce = end - cb; if (ce > 32u) ce = 32u;
    if (tid < (int)ce) {
      int e = csr[cb + tid];
      dl[tid] = ei[NE + e];
      ewl[tid] = ew[e];
    }
    __syncthreads();
    for (int idx = tid; idx < (int)ce * NSTEP; idx += 128) {
      int el = idx >> 5, t = idx & 31;
      float v = beta[dl[el] * NSTEP + t] * ewl[el];
      g[el][t] = expf(v - m[t]) / den[t];
    }
    __syncthreads();
    for (int el = 0; el < (int)ce; ++el)
      acc += V[dl[el] * OC + c] * g[el][tq];
    __syncthreads();
  }
  out[n * OC + c] = acc;
}

// --------------------------------------------------------------------- host
extern "C" void kernel_launch(void* const* d_in, const int* in_sizes, int n_in,
                              void* d_out, int out_size, void* d_ws, size_t ws_size,
                              hipStream_t stream) {
  const float* x     = (const float*)d_in[0];
  const float* p_t   = (const float*)d_in[1];
  const int*   ei    = (const int*)d_in[2];
  const float* ew    = (const float*)d_in[3];
  const float* lin_w = (const float*)d_in[4];
  const float* lin_b = (const float*)d_in[5];
  const float* inc_w = (const float*)d_in[6];
  const float* inc_b = (const float*)d_in[7];
  const float* mw    = (const float*)d_in[8];
  float* out = (float*)d_out;

  char* w = (char*)d_ws;
  size_t off = 0;
  auto alloc = [&](size_t b) -> void* {
    void* p = w + off;
    off += (b + 511) & ~(size_t)511;
    return p;
  };
  float*  Wq    = (float*)alloc((size_t)33 * NQCOL * 4 * 4);
  double* Ud    = (double*)alloc((size_t)17 * IC * 8);
  double* ubd   = (double*)alloc(17 * 8);
  float*  beta  = (float*)alloc((size_t)NN * NSTEP * 4);
  double* s64   = (double*)alloc((size_t)NN * 8);
  float*  V     = (float*)alloc((size_t)NN * OC * 4);
  unsigned long long* keys  = (unsigned long long*)alloc((size_t)NE * 8);
  unsigned long long* candk = (unsigned long long*)alloc((size_t)CANDCAP * 8);
  int*      cande  = (int*)alloc((size_t)CANDCAP * 4);
  int*      sel    = (int*)alloc((size_t)KSEL * 4);
  unsigned* cnt    = (unsigned*)alloc((size_t)NN * 4);
  unsigned* offar  = (unsigned*)alloc((size_t)(NN + 1) * 4);
  unsigned* cursor = (unsigned*)alloc((size_t)NN * 4);
  int*      csr    = (int*)alloc((size_t)KSEL * 4);
  unsigned* hist   = (unsigned*)alloc(512 * 4);
  unsigned* bsum   = (unsigned*)alloc(NB * 4);
  unsigned* bbase  = (unsigned*)alloc(NB * 4);
  SelState* st     = (SelState*)alloc(sizeof(SelState));
  if (off > ws_size) return;

  int init_threads = 33 * NQCOL + 17 * IC + 17 + NN + 512 + 1;
  k_init<<<(init_threads + 255) / 256, 256, 0, stream>>>(p_t, lin_w, inc_w, inc_b,
                                                         Wq, Ud, ubd, cnt, hist, st);
  k_init2<<<1, 128, 0, stream>>>(lin_b, Wq);
  k_node<<<((NN + 63) / 64) * 4, 256, 0, stream>>>(x, mw, Wq, Ud, ubd, beta, s64, V);
  k_key<<<(NE + 255) / 256, 256, 0, stream>>>(ei, ew, s64, keys);
  k_radix<<<256, 256, 0, stream>>>(keys, hist, st, 0);
  k_radix<<<256, 256, 0, stream>>>(keys, hist, st, 1);
  k_cand<<<(NE + 255) / 256, 256, 0, stream>>>(keys, st, candk, cande);
  k_sel<<<1, 256, 0, stream>>>(candk, cande, ei, st, sel, cnt);
  k_compact<<<(NE + 255) / 256, 256, 0, stream>>>(keys, ei, st, sel, cnt);
  k_pref1<<<NB, 256, 0, stream>>>(cnt, bsum);
  k_pref2<<<1, 128, 0, stream>>>(bsum, bbase, offar);
  k_pref3<<<NB, 256, 0, stream>>>(cnt, bbase, offar, cursor);
  k_scatter<<<(KSEL + 255) / 256, 256, 0, stream>>>(sel, ei, cursor, csr);
  k_out<<<NN, 128, 0, stream>>>(ei, ew, beta, V, offar, csr, out);
}

// Round 7
// 352.279 us; speedup vs baseline: 1.4007x; 1.4007x over previous
//
#include <hip/hip_runtime.h>

#define NN 20000
#define IC 128
#define OC 128
#define NSTEP 32
#define NE 256000
#define KSEL 128000
#define NB 79        // prefix-scan blocks = ceil(NN/256)
#define CANDCAP 131072
#define NQCOL 704    // 512 beta + 32 p + 128 V + 32 pad

struct SelState {
  unsigned long long prefix;
  unsigned r;       // remaining rank
  unsigned selc;    // selected count
  unsigned tiec;    // candidate count
  unsigned done[8]; // block-done counters
};

typedef __attribute__((ext_vector_type(16))) float f16v;

// ---------------------------------------------------------------- init / fold
// Wq layout: float4 index = k4*NQCOL + col ; element jj = W[col][4*k4+jj]
// k4=0..31 weights; k4==32 = bias row (elements jj>0 are 0); cols 672..703 = 0
__global__ void k_init(const float* __restrict__ p_t, const float* __restrict__ lin_w,
                       const float* __restrict__ inc_w, const float* __restrict__ inc_b,
                       float* __restrict__ Wq,
                       double* __restrict__ Ud, double* __restrict__ ubd,
                       unsigned* __restrict__ cnt, unsigned* __restrict__ hist,
                       SelState* st) {
  int i = blockIdx.x * blockDim.x + threadIdx.x;
  if (i < 33 * NQCOL) {
    int k4 = i / NQCOL, col = i - k4 * NQCOL;
    float4 o;
    float* ov = (float*)&o;
    for (int jj = 0; jj < 4; ++jj) {
      int k = 4 * k4 + jj;
      float v = 0.f;
      if (col < 512) {
        int t = col >> 4, c = col & 15;
        if (k < 128) v = inc_w[k * 1024 + t * 32 + c];
        else if (k == 128) v = inc_b[t * 32 + c];
      } else if (col < 544) {
        int t = col - 512;
        if (k < 128) {
          float a = 0.f;
          for (int q = 0; q < 16; ++q) a += inc_w[k * 1024 + t * 32 + 16 + q] * p_t[t * 16 + q];
          v = a;
        } else if (k == 128) {
          float a = 0.f;
          for (int q = 0; q < 16; ++q) a += inc_b[t * 32 + 16 + q] * p_t[t * 16 + q];
          v = a;
        }
      } else if (col < 672) {
        int c = col - 544;
        if (k < 128) v = lin_w[k * OC + c];
        // k==128 (bias) patched by k_init2
      }
      ov[jj] = v;
    }
    ((float4*)Wq)[i] = o;
    return;
  }
  i -= 33 * NQCOL;
  if (i < 17 * IC) {  // f64 folded selection columns: U (16) and q (1)
    int c = i >> 7, k = i & 127;
    double a = 0.0;
    if (c < 16) {
      for (int t = 0; t < NSTEP; ++t) a += (double)inc_w[k * 1024 + t * 32 + c];
    } else {
      for (int t = 0; t < NSTEP; ++t)
        for (int q = 0; q < 16; ++q)
          a += (double)inc_w[k * 1024 + t * 32 + 16 + q] * (double)p_t[t * 16 + q];
    }
    Ud[c * IC + k] = a;
    return;
  }
  i -= 17 * IC;
  if (i < 17) {
    double a = 0.0;
    if (i < 16) {
      for (int t = 0; t < NSTEP; ++t) a += (double)inc_b[t * 32 + i];
    } else {
      for (int t = 0; t < NSTEP; ++t)
        for (int q = 0; q < 16; ++q)
          a += (double)inc_b[t * 32 + 16 + q] * (double)p_t[t * 16 + q];
    }
    ubd[i] = a;
    return;
  }
  i -= 17;
  if (i < NN) { cnt[i] = 0u; return; }
  i -= NN;
  if (i < 512) { hist[i] = 0u; return; }
  i -= 512;
  if (i == 0) {
    st->prefix = 0ull; st->r = KSEL; st->selc = 0u; st->tiec = 0u;
    for (int p = 0; p < 8; ++p) st->done[p] = 0u;
  }
}

// patch: bias row for V columns (k==128 -> k4==32, element 0)
__global__ void k_init2(const float* __restrict__ lin_b, float* __restrict__ Wq) {
  int c = threadIdx.x;  // 0..127
  Wq[((size_t)32 * NQCOL + 544 + c) * 4 + 0] = lin_b[c];
}

// ---------------- f32 per-node GEMM: uniform (scalar) weights, double-buffered
// grid = dim3(313, 5); block = 4 waves; split s covers units s*8..s*8+7;
// wave j does units s*8+j and s*8+j+4.
//   units 0..31 : beta timestep t (16 w_v cols + 1 p col, finalized in-reg)
//   units 32..39: V column group (16 cols)
#define FMA4(WV, BASE)                                                                        \
  acc[BASE+0] = fmaf(xf.x, WV[0],  fmaf(xf.y, WV[1],  fmaf(xf.z, WV[2],  fmaf(xf.w, WV[3],  acc[BASE+0])))); \
  acc[BASE+1] = fmaf(xf.x, WV[4],  fmaf(xf.y, WV[5],  fmaf(xf.z, WV[6],  fmaf(xf.w, WV[7],  acc[BASE+1])))); \
  acc[BASE+2] = fmaf(xf.x, WV[8],  fmaf(xf.y, WV[9],  fmaf(xf.z, WV[10], fmaf(xf.w, WV[11], acc[BASE+2])))); \
  acc[BASE+3] = fmaf(xf.x, WV[12], fmaf(xf.y, WV[13], fmaf(xf.z, WV[14], fmaf(xf.w, WV[15], acc[BASE+3]))));

__global__ __launch_bounds__(256) void k_node(
    const float* __restrict__ x, const float* __restrict__ mw,
    const float* __restrict__ Wq,
    float* __restrict__ beta, float* __restrict__ V) {
  __shared__ float4 xl[64 * 32];       // rotated: [m*32 + ((k4+m)&31)]
  int tid = threadIdx.x;
  int g = blockIdx.x;                  // node group
  int s = blockIdx.y;                  // split 0..4
  int n0 = g * 64;
  int nvalid = NN - n0; if (nvalid > 64) nvalid = 64;

  for (int i = tid; i < 64 * 32; i += 256) {
    int mm = i >> 5, k4 = i & 31;
    float4 v = make_float4(0.f, 0.f, 0.f, 0.f);
    if (mm < nvalid) v = ((const float4*)(x + (size_t)(n0 + mm) * IC))[k4];
    xl[(mm << 5) + ((k4 + mm) & 31)] = v;
  }
  int m = tid & 63;
  int j = __builtin_amdgcn_readfirstlane(threadIdx.x >> 6);  // wave id 0..3
  __syncthreads();

  for (int r = 0; r < 2; ++r) {
    int u = s * 8 + j + r * 4;         // uniform unit index
    if (u < 32) {                       // ---- beta unit, timestep t = u
      float mwr[16];
      {
        int mm = (m < nvalid) ? m : 0;
        const float4* mp = (const float4*)(mw + (size_t)(n0 + mm) * 16);
#pragma unroll
        for (int i = 0; i < 4; ++i) {
          float4 t4 = mp[i];
          mwr[4 * i] = t4.x; mwr[4 * i + 1] = t4.y; mwr[4 * i + 2] = t4.z; mwr[4 * i + 3] = t4.w;
        }
      }
      const f16v*   wb = (const f16v*)Wq + (u << 2);      // cols u*16..u*16+15
      const float4* wp = (const float4*)Wq + (512 + u);   // p-col
      float acc[16], accp;
      {
        const f16v* wkb = wb + 32 * 176;
        f16v b0 = wkb[0], b1 = wkb[1], b2 = wkb[2], b3 = wkb[3];
#pragma unroll
        for (int c = 0; c < 4; ++c) {
          acc[c] = b0[4 * c]; acc[4 + c] = b1[4 * c];
          acc[8 + c] = b2[4 * c]; acc[12 + c] = b3[4 * c];
        }
        accp = wp[32 * NQCOL].x;
      }
      f16v w0 = wb[0], w1 = wb[1], w2 = wb[2], w3 = wb[3];
      float4 pw = wp[0];
      for (int k4 = 0; k4 < 32; ++k4) {
        f16v nw0, nw1, nw2, nw3; float4 npw;
        if (k4 < 31) {
          const f16v* wn = wb + (k4 + 1) * 176;
          nw0 = wn[0]; nw1 = wn[1]; nw2 = wn[2]; nw3 = wn[3];
          npw = wp[(k4 + 1) * NQCOL];
        }
        float4 xf = xl[(m << 5) + ((k4 + m) & 31)];
        FMA4(w0, 0) FMA4(w1, 4) FMA4(w2, 8) FMA4(w3, 12)
        accp = fmaf(xf.x, pw.x, fmaf(xf.y, pw.y, fmaf(xf.z, pw.z, fmaf(xf.w, pw.w, accp))));
        if (k4 < 31) { w0 = nw0; w1 = nw1; w2 = nw2; w3 = nw3; pw = npw; }
      }
      float bs = accp;
#pragma unroll
      for (int c = 0; c < 16; ++c) bs = fmaf(acc[c], mwr[c], bs);
      if (m < nvalid) beta[(size_t)(n0 + m) * NSTEP + u] = bs * (1.f / 32.f);
    } else {                            // ---- V unit, cols vc0..vc0+15
      int vg = u - 32;
      int vc0 = vg << 4;
      const f16v* wb = (const f16v*)Wq + 136 + (vg << 2);
      float acc[16];
      {
        const f16v* wkb = wb + 32 * 176;
        f16v b0 = wkb[0], b1 = wkb[1], b2 = wkb[2], b3 = wkb[3];
#pragma unroll
        for (int c = 0; c < 4; ++c) {
          acc[c] = b0[4 * c]; acc[4 + c] = b1[4 * c];
          acc[8 + c] = b2[4 * c]; acc[12 + c] = b3[4 * c];
        }
      }
      f16v w0 = wb[0], w1 = wb[1], w2 = wb[2], w3 = wb[3];
      for (int k4 = 0; k4 < 32; ++k4) {
        f16v nw0, nw1, nw2, nw3;
        if (k4 < 31) {
          const f16v* wn = wb + (k4 + 1) * 176;
          nw0 = wn[0]; nw1 = wn[1]; nw2 = wn[2]; nw3 = wn[3];
        }
        float4 xf = xl[(m << 5) + ((k4 + m) & 31)];
        FMA4(w0, 0) FMA4(w1, 4) FMA4(w2, 8) FMA4(w3, 12)
        if (k4 < 31) { w0 = nw0; w1 = nw1; w2 = nw2; w3 = nw3; }
      }
      if (m < nvalid) {
        float* vout = V + (size_t)(n0 + m) * OC + vc0;
#pragma unroll
        for (int q = 0; q < 4; ++q) {
          float4 o;
          o.x = fmaxf(acc[4 * q], 0.f);     o.y = fmaxf(acc[4 * q + 1], 0.f);
          o.z = fmaxf(acc[4 * q + 2], 0.f); o.w = fmaxf(acc[4 * q + 3], 0.f);
          ((float4*)vout)[q] = o;
        }
      }
    }
  }
}

// ---------------- f64 selection scalar (exact top-k path), own kernel
__global__ __launch_bounds__(256) void k_s64(
    const float* __restrict__ x, const float* __restrict__ mw,
    const double* __restrict__ Ud, const double* __restrict__ ubd,
    double* __restrict__ s64) {
  __shared__ float4 xl[64 * 32];
  __shared__ double sdd[64][18];
  int tid = threadIdx.x;
  int n0 = blockIdx.x * 64;
  int nvalid = NN - n0; if (nvalid > 64) nvalid = 64;

  for (int i = tid; i < 64 * 32; i += 256) {
    int mm = i >> 5, k4 = i & 31;
    float4 v = make_float4(0.f, 0.f, 0.f, 0.f);
    if (mm < nvalid) v = ((const float4*)(x + (size_t)(n0 + mm) * IC))[k4];
    xl[(mm << 5) + ((k4 + mm) & 31)] = v;
  }
  __syncthreads();
  int m = tid & 63, j = tid >> 6;
  for (int c = j; c < 17; c += 4) {
    const double* uc = Ud + c * IC;
    double a0 = 0.0, a1 = 0.0, a2 = 0.0, a3 = 0.0;
    for (int k4 = 0; k4 < 32; ++k4) {
      float4 xv = xl[(m << 5) + ((k4 + m) & 31)];
      a0 = fma((double)xv.x, uc[4 * k4],     a0);
      a1 = fma((double)xv.y, uc[4 * k4 + 1], a1);
      a2 = fma((double)xv.z, uc[4 * k4 + 2], a2);
      a3 = fma((double)xv.w, uc[4 * k4 + 3], a3);
    }
    sdd[m][c] = (a0 + a1) + (a2 + a3);
  }
  __syncthreads();
  if (tid < 64 && tid < nvalid) {
    const float* mp = mw + (size_t)(n0 + tid) * 16;
    double ssum = sdd[tid][16] + ubd[16];
#pragma unroll
    for (int c = 0; c < 16; ++c) ssum += (sdd[tid][c] + ubd[c]) * (double)mp[c];
    s64[n0 + tid] = ssum * (1.0 / 1024.0);
  }
}

// ---------------------------------------------------------------- edge keys
__global__ void k_key(const int* __restrict__ ei, const float* __restrict__ ew,
                      const double* __restrict__ s64, unsigned long long* __restrict__ keys) {
  int e = blockIdx.x * 256 + threadIdx.x;
  if (e >= NE) return;
  int d = ei[NE + e];
  double v = s64[d] * (double)ew[e];
  unsigned long long u = (unsigned long long)__double_as_longlong(v);
  u = (u & 0x8000000000000000ull) ? ~u : (u | 0x8000000000000000ull);
  keys[e] = u;
}

// ------------------- radix select pass (hist + parallel suffix-scan pick)
__global__ void k_radix(const unsigned long long* __restrict__ keys,
                        unsigned* __restrict__ hist, SelState* st, int p) {
  __shared__ unsigned h[256], suf[256];
  __shared__ int last;
  int tid = threadIdx.x;
  h[tid] = 0u;
  if (tid == 0) last = 0;
  unsigned long long pref = (p == 0) ? 0ull : st->prefix;
  __syncthreads();
  int shift = 56 - 8 * p;
  unsigned* hp = hist + p * 256;
  for (int e = blockIdx.x * 256 + tid; e < NE; e += gridDim.x * 256) {
    unsigned long long k = keys[e];
    if (p == 0 || (k >> (shift + 8)) == pref)
      atomicAdd(&h[(unsigned)((k >> shift) & 255ull)], 1u);
  }
  __syncthreads();
  if (h[tid]) atomicAdd(&hp[tid], h[tid]);
  __threadfence();
  __syncthreads();
  if (tid == 0) {
    unsigned old = atomicAdd(&st->done[p], 1u);
    if (old == gridDim.x - 1) last = 1;
  }
  __syncthreads();
  if (!last) return;
  unsigned c = atomicAdd(&hp[tid], 0u);
  suf[tid] = c;
  __syncthreads();
  for (int d = 1; d < 256; d <<= 1) {
    unsigned v = (tid + d < 256) ? suf[tid + d] : 0u;
    __syncthreads();
    suf[tid] += v;
    __syncthreads();
  }
  unsigned r = st->r;
  unsigned exc = suf[tid] - c;
  if (exc < r && exc + c >= r) {
    st->prefix = (st->prefix << 8) | (unsigned long long)tid;
    st->r = r - exc;
  }
}

// ------------------- collect candidates matching the 16-bit prefix
__global__ void k_cand(const unsigned long long* __restrict__ keys, SelState* st,
                       unsigned long long* __restrict__ candk, int* __restrict__ cande) {
  int e = blockIdx.x * 256 + threadIdx.x;
  if (e >= NE) return;
  unsigned long long k = keys[e];
  if ((unsigned)(k >> 48) == (unsigned)st->prefix) {
    unsigned pos = atomicAdd(&st->tiec, 1u);
    if (pos < CANDCAP) { candk[pos] = k; cande[pos] = e; }
  }
}

// ----------- single block: resolve bytes 2..7 over candidates + tie select
__global__ void k_sel(const unsigned long long* __restrict__ candk,
                      const int* __restrict__ cande, const int* __restrict__ ei,
                      SelState* st, int* __restrict__ sel, unsigned* __restrict__ cnt) {
  __shared__ unsigned h[256], suf[256];
  __shared__ unsigned long long spref;
  __shared__ unsigned sr;
  int tid = threadIdx.x;
  unsigned C = st->tiec; if (C > CANDCAP) C = CANDCAP;
  if (tid == 0) { spref = st->prefix; sr = st->r; }
  __syncthreads();
  for (int p = 2; p < 8; ++p) {
    h[tid] = 0u;
    __syncthreads();
    int shift = 56 - 8 * p;
    unsigned long long pf = spref;
    unsigned r = sr;
    for (unsigned i = tid; i < C; i += 256) {
      unsigned long long k = candk[i];
      if ((k >> (shift + 8)) == pf) atomicAdd(&h[(unsigned)((k >> shift) & 255ull)], 1u);
    }
    __syncthreads();
    suf[tid] = h[tid];
    __syncthreads();
    for (int d = 1; d < 256; d <<= 1) {
      unsigned v = (tid + d < 256) ? suf[tid + d] : 0u;
      __syncthreads();
      suf[tid] += v;
      __syncthreads();
    }
    unsigned exc = suf[tid] - h[tid];
    if (exc < r && exc + h[tid] >= r) {
      spref = (pf << 8) | (unsigned long long)tid;
      sr = r - exc;
    }
    __syncthreads();
  }
  unsigned long long T = spref;
  unsigned needed = sr;
  if (tid == 0) { st->prefix = T; st->r = needed; }
  // ties: take lowest-index `needed` among keys == T
  for (unsigned i = tid; i < C; i += 256) {
    if (candk[i] == T) {
      int e = cande[i];
      unsigned rank = 0;
      for (unsigned q = 0; q < C; ++q)
        rank += (candk[q] == T && cande[q] < e) ? 1u : 0u;
      if (rank < needed) {
        unsigned pos = atomicAdd(&st->selc, 1u);
        if (pos < KSEL) { sel[pos] = e; atomicAdd(&cnt[ei[e]], 1u); }
      }
    }
  }
}

// --------------------------------------------------- selection (> T) + counts
__global__ void k_compact(const unsigned long long* __restrict__ keys,
                          const int* __restrict__ ei, SelState* st,
                          int* __restrict__ sel, unsigned* __restrict__ cnt) {
  int e = blockIdx.x * 256 + threadIdx.x;
  if (e >= NE) return;
  if (keys[e] > st->prefix) {
    unsigned pos = atomicAdd(&st->selc, 1u);
    if (pos < KSEL) { sel[pos] = e; atomicAdd(&cnt[ei[e]], 1u); }
  }
}

// ----------------------------------------------- 3-phase prefix sum -> CSR
__global__ void k_pref1(const unsigned* __restrict__ cnt, unsigned* __restrict__ bsum) {
  __shared__ unsigned sd[256];
  int i = blockIdx.x * 256 + threadIdx.x;
  sd[threadIdx.x] = (i < NN) ? cnt[i] : 0u;
  __syncthreads();
  for (int s = 128; s > 0; s >>= 1) {
    if (threadIdx.x < s) sd[threadIdx.x] += sd[threadIdx.x + s];
    __syncthreads();
  }
  if (threadIdx.x == 0) bsum[blockIdx.x] = sd[0];
}

__global__ void k_pref2(const unsigned* __restrict__ bsum, unsigned* __restrict__ bbase,
                        unsigned* __restrict__ offar) {
  __shared__ unsigned sd[128];
  int tid = threadIdx.x;
  unsigned v = (tid < NB) ? bsum[tid] : 0u;
  sd[tid] = v;
  __syncthreads();
  for (int d = 1; d < 128; d <<= 1) {
    unsigned u = (tid >= d) ? sd[tid - d] : 0u;
    __syncthreads();
    sd[tid] += u;
    __syncthreads();
  }
  if (tid < NB) bbase[tid] = sd[tid] - v;
  if (tid == NB - 1) offar[NN] = sd[tid];
}

__global__ void k_pref3(const unsigned* __restrict__ cnt, const unsigned* __restrict__ bbase,
                        unsigned* __restrict__ offar, unsigned* __restrict__ cursor) {
  __shared__ unsigned sd[256];
  int tid = threadIdx.x;
  int i = blockIdx.x * 256 + tid;
  unsigned v = (i < NN) ? cnt[i] : 0u;
  sd[tid] = v;
  __syncthreads();
  for (int d = 1; d < 256; d <<= 1) {
    unsigned u = (tid >= d) ? sd[tid - d] : 0u;
    __syncthreads();
    sd[tid] += u;
    __syncthreads();
  }
  if (i < NN) {
    unsigned excl = bbase[blockIdx.x] + sd[tid] - v;
    offar[i] = excl;
    cursor[i] = excl;
  }
}

__global__ void k_scatter(const int* __restrict__ sel, const int* __restrict__ ei,
                          unsigned* __restrict__ cursor, int* __restrict__ csr) {
  int i = blockIdx.x * 256 + threadIdx.x;
  if (i >= KSEL) return;
  int e = sel[i];
  unsigned pos = atomicAdd(&cursor[ei[e]], 1u);
  if (pos < KSEL) csr[pos] = e;
}

// ------------------------------------- per-node softmax + weighted scatter
__global__ __launch_bounds__(128) void k_out(
    const int* __restrict__ ei, const float* __restrict__ ew,
    const float* __restrict__ beta, const float* __restrict__ V,
    const unsigned* __restrict__ offar, const int* __restrict__ csr,
    float* __restrict__ out) {
  __shared__ float m[NSTEP], den[NSTEP];
  __shared__ float g[32][NSTEP];
  __shared__ int dl[32];
  __shared__ float ewl[32];
  int n = blockIdx.x, tid = threadIdx.x;
  unsigned beg = offar[n], end = offar[n + 1];
  if (end > (unsigned)KSEL) end = KSEL;
  if (beg > end) beg = end;
  if (tid < NSTEP) {
    float mm = -INFINITY;
    for (unsigned i = beg; i < end; ++i) {
      int e = csr[i]; int d = ei[NE + e];
      float v = beta[d * NSTEP + tid] * ew[e];
      mm = fmaxf(mm, v);
    }
    m[tid] = mm;
    float dd = 0.f;
    for (unsigned i = beg; i < end; ++i) {
      int e = csr[i]; int d = ei[NE + e];
      float v = beta[d * NSTEP + tid] * ew[e];
      dd += expf(v - mm);
    }
    den[tid] = dd;
  }
  __syncthreads();
  float acc = 0.f;
  int c = tid, tq = tid >> 2;
  for (unsigned cb = beg; cb < end; cb += 32u) {
    unsigned ce = end - cb; if (ce > 32u) ce = 32u;
    if (tid < (int)ce) {
      int e = csr[cb + tid];
      dl[tid] = ei[NE + e];
      ewl[tid] = ew[e];
    }
    __syncthreads();
    for (int idx = tid; idx < (int)ce * NSTEP; idx += 128) {
      int el = idx >> 5, t = idx & 31;
      float v = beta[dl[el] * NSTEP + t] * ewl[el];
      g[el][t] = expf(v - m[t]) / den[t];
    }
    __syncthreads();
    for (int el = 0; el < (int)ce; ++el)
      acc += V[dl[el] * OC + c] * g[el][tq];
    __syncthreads();
  }
  out[n * OC + c] = acc;
}

// --------------------------------------------------------------------- host
extern "C" void kernel_launch(void* const* d_in, const int* in_sizes, int n_in,
                              void* d_out, int out_size, void* d_ws, size_t ws_size,
                              hipStream_t stream) {
  const float* x     = (const float*)d_in[0];
  const float* p_t   = (const float*)d_in[1];
  const int*   ei    = (const int*)d_in[2];
  const float* ew    = (const float*)d_in[3];
  const float* lin_w = (const float*)d_in[4];
  const float* lin_b = (const float*)d_in[5];
  const float* inc_w = (const float*)d_in[6];
  const float* inc_b = (const float*)d_in[7];
  const float* mw    = (const float*)d_in[8];
  float* out = (float*)d_out;

  char* w = (char*)d_ws;
  size_t off = 0;
  auto alloc = [&](size_t b) -> void* {
    void* p = w + off;
    off += (b + 511) & ~(size_t)511;
    return p;
  };
  float*  Wq    = (float*)alloc((size_t)33 * NQCOL * 4 * 4);
  double* Ud    = (double*)alloc((size_t)17 * IC * 8);
  double* ubd   = (double*)alloc(17 * 8);
  float*  beta  = (float*)alloc((size_t)NN * NSTEP * 4);
  double* s64   = (double*)alloc((size_t)NN * 8);
  float*  V     = (float*)alloc((size_t)NN * OC * 4);
  unsigned long long* keys  = (unsigned long long*)alloc((size_t)NE * 8);
  unsigned long long* candk = (unsigned long long*)alloc((size_t)CANDCAP * 8);
  int*      cande  = (int*)alloc((size_t)CANDCAP * 4);
  int*      sel    = (int*)alloc((size_t)KSEL * 4);
  unsigned* cnt    = (unsigned*)alloc((size_t)NN * 4);
  unsigned* offar  = (unsigned*)alloc((size_t)(NN + 1) * 4);
  unsigned* cursor = (unsigned*)alloc((size_t)NN * 4);
  int*      csr    = (int*)alloc((size_t)KSEL * 4);
  unsigned* hist   = (unsigned*)alloc(512 * 4);
  unsigned* bsum   = (unsigned*)alloc(NB * 4);
  unsigned* bbase  = (unsigned*)alloc(NB * 4);
  SelState* st     = (SelState*)alloc(sizeof(SelState));
  if (off > ws_size) return;

  int init_threads = 33 * NQCOL + 17 * IC + 17 + NN + 512 + 1;
  k_init<<<(init_threads + 255) / 256, 256, 0, stream>>>(p_t, lin_w, inc_w, inc_b,
                                                         Wq, Ud, ubd, cnt, hist, st);
  k_init2<<<1, 128, 0, stream>>>(lin_b, Wq);
  k_node<<<dim3((NN + 63) / 64, 5), 256, 0, stream>>>(x, mw, Wq, beta, V);
  k_s64<<<(NN + 63) / 64, 256, 0, stream>>>(x, mw, Ud, ubd, s64);
  k_key<<<(NE + 255) / 256, 256, 0, stream>>>(ei, ew, s64, keys);
  k_radix<<<256, 256, 0, stream>>>(keys, hist, st, 0);
  k_radix<<<256, 256, 0, stream>>>(keys, hist, st, 1);
  k_cand<<<(NE + 255) / 256, 256, 0, stream>>>(keys, st, candk, cande);
  k_sel<<<1, 256, 0, stream>>>(candk, cande, ei, st, sel, cnt);
  k_compact<<<(NE + 255) / 256, 256, 0, stream>>>(keys, ei, st, sel, cnt);
  k_pref1<<<NB, 256, 0, stream>>>(cnt, bsum);
  k_pref2<<<1, 128, 0, stream>>>(bsum, bbase, offar);
  k_pref3<<<NB, 256, 0, stream>>>(cnt, bbase, offar, cursor);
  k_scatter<<<(KSEL + 255) / 256, 256, 0, stream>>>(sel, ei, cursor, csr);
  k_out<<<NN, 128, 0, stream>>>(ei, ew, beta, V, offar, csr, out);
}

// Round 8
// 339.370 us; speedup vs baseline: 1.4540x; 1.0380x over previous
//
#include <hip/hip_runtime.h>

#define NN 20000
#define IC 128
#define OC 128
#define NSTEP 32
#define NE 256000
#define KSEL 128000
#define NB 79        // prefix-scan blocks = ceil(NN/256)
#define CANDCAP 131072
#define NQCOL 704    // 512 beta + 32 p + 128 V + 32 pad

struct SelState {
  unsigned long long prefix;
  unsigned r;       // remaining rank
  unsigned selc;    // selected count
  unsigned tiec;    // candidate count
  unsigned done[8]; // block-done counters
};

typedef __attribute__((ext_vector_type(16))) float f16v;

// ---------------------------------------------------------------- init / fold
// Wq layout: float4 index = k4*NQCOL + col ; element jj = W[col][4*k4+jj]
// k4=0..31 weights; k4==32 = bias row (elements jj>0 are 0); cols 672..703 = 0
__global__ void k_init(const float* __restrict__ p_t, const float* __restrict__ lin_w,
                       const float* __restrict__ lin_b,
                       const float* __restrict__ inc_w, const float* __restrict__ inc_b,
                       float* __restrict__ Wq,
                       double* __restrict__ Ud, double* __restrict__ ubd,
                       unsigned* __restrict__ cnt, unsigned* __restrict__ hist,
                       SelState* st) {
  int i = blockIdx.x * blockDim.x + threadIdx.x;
  if (i < 33 * NQCOL) {
    int k4 = i / NQCOL, col = i - k4 * NQCOL;
    float4 o;
    float* ov = (float*)&o;
    for (int jj = 0; jj < 4; ++jj) {
      int k = 4 * k4 + jj;
      float v = 0.f;
      if (col < 512) {
        int t = col >> 4, c = col & 15;
        if (k < 128) v = inc_w[k * 1024 + t * 32 + c];
        else if (k == 128) v = inc_b[t * 32 + c];
      } else if (col < 544) {
        int t = col - 512;
        if (k < 128) {
          float a = 0.f;
          for (int q = 0; q < 16; ++q) a += inc_w[k * 1024 + t * 32 + 16 + q] * p_t[t * 16 + q];
          v = a;
        } else if (k == 128) {
          float a = 0.f;
          for (int q = 0; q < 16; ++q) a += inc_b[t * 32 + 16 + q] * p_t[t * 16 + q];
          v = a;
        }
      } else if (col < 672) {
        int c = col - 544;
        if (k < 128) v = lin_w[k * OC + c];
        else if (k == 128) v = lin_b[c];
      }
      ov[jj] = v;
    }
    ((float4*)Wq)[i] = o;
    return;
  }
  i -= 33 * NQCOL;
  if (i < 17 * IC) {  // f64 folded selection columns: U (16) and q (1)
    int c = i >> 7, k = i & 127;
    double a = 0.0;
    if (c < 16) {
      for (int t = 0; t < NSTEP; ++t) a += (double)inc_w[k * 1024 + t * 32 + c];
    } else {
      for (int t = 0; t < NSTEP; ++t)
        for (int q = 0; q < 16; ++q)
          a += (double)inc_w[k * 1024 + t * 32 + 16 + q] * (double)p_t[t * 16 + q];
    }
    Ud[c * IC + k] = a;
    return;
  }
  i -= 17 * IC;
  if (i < 17) {
    double a = 0.0;
    if (i < 16) {
      for (int t = 0; t < NSTEP; ++t) a += (double)inc_b[t * 32 + i];
    } else {
      for (int t = 0; t < NSTEP; ++t)
        for (int q = 0; q < 16; ++q)
          a += (double)inc_b[t * 32 + 16 + q] * (double)p_t[t * 16 + q];
    }
    ubd[i] = a;
    return;
  }
  i -= 17;
  if (i < NN) { cnt[i] = 0u; return; }
  i -= NN;
  if (i < 512) { hist[i] = 0u; return; }
  i -= 512;
  if (i == 0) {
    st->prefix = 0ull; st->r = KSEL; st->selc = 0u; st->tiec = 0u;
    for (int p = 0; p < 8; ++p) st->done[p] = 0u;
  }
}

// ---------------- f32 per-node GEMM: uniform (scalar) weights, double-buffered
// grid = dim3(313, 5); block = 4 waves; split s covers units s*8..s*8+7;
// wave j does units s*8+j and s*8+j+4.
//   units 0..31 : beta timestep t (16 w_v cols + 1 p col, finalized in-reg)
//   units 32..39: V column group (16 cols)
#define FMA4(WV, BASE)                                                                        \
  acc[BASE+0] = fmaf(xf.x, WV[0],  fmaf(xf.y, WV[1],  fmaf(xf.z, WV[2],  fmaf(xf.w, WV[3],  acc[BASE+0])))); \
  acc[BASE+1] = fmaf(xf.x, WV[4],  fmaf(xf.y, WV[5],  fmaf(xf.z, WV[6],  fmaf(xf.w, WV[7],  acc[BASE+1])))); \
  acc[BASE+2] = fmaf(xf.x, WV[8],  fmaf(xf.y, WV[9],  fmaf(xf.z, WV[10], fmaf(xf.w, WV[11], acc[BASE+2])))); \
  acc[BASE+3] = fmaf(xf.x, WV[12], fmaf(xf.y, WV[13], fmaf(xf.z, WV[14], fmaf(xf.w, WV[15], acc[BASE+3]))));

__global__ __launch_bounds__(256) void k_node(
    const float* __restrict__ x, const float* __restrict__ mw,
    const float* __restrict__ Wq,
    float* __restrict__ beta, float* __restrict__ V) {
  __shared__ float4 xl[64 * 32];       // rotated: [m*32 + ((k4+m)&31)]
  int tid = threadIdx.x;
  int g = blockIdx.x;                  // node group
  int s = blockIdx.y;                  // split 0..4
  int n0 = g * 64;
  int nvalid = NN - n0; if (nvalid > 64) nvalid = 64;

  for (int i = tid; i < 64 * 32; i += 256) {
    int mm = i >> 5, k4 = i & 31;
    float4 v = make_float4(0.f, 0.f, 0.f, 0.f);
    if (mm < nvalid) v = ((const float4*)(x + (size_t)(n0 + mm) * IC))[k4];
    xl[(mm << 5) + ((k4 + mm) & 31)] = v;
  }
  int m = tid & 63;
  int j = __builtin_amdgcn_readfirstlane(threadIdx.x >> 6);  // wave id 0..3
  __syncthreads();

  for (int r = 0; r < 2; ++r) {
    int u = s * 8 + j + r * 4;         // uniform unit index
    if (u < 32) {                       // ---- beta unit, timestep t = u
      float mwr[16];
      {
        int mm = (m < nvalid) ? m : 0;
        const float4* mp = (const float4*)(mw + (size_t)(n0 + mm) * 16);
#pragma unroll
        for (int i = 0; i < 4; ++i) {
          float4 t4 = mp[i];
          mwr[4 * i] = t4.x; mwr[4 * i + 1] = t4.y; mwr[4 * i + 2] = t4.z; mwr[4 * i + 3] = t4.w;
        }
      }
      const f16v*   wb = (const f16v*)Wq + (u << 2);      // cols u*16..u*16+15
      const float4* wp = (const float4*)Wq + (512 + u);   // p-col
      float acc[16], accp;
      {
        const f16v* wkb = wb + 32 * 176;
        f16v b0 = wkb[0], b1 = wkb[1], b2 = wkb[2], b3 = wkb[3];
#pragma unroll
        for (int c = 0; c < 4; ++c) {
          acc[c] = b0[4 * c]; acc[4 + c] = b1[4 * c];
          acc[8 + c] = b2[4 * c]; acc[12 + c] = b3[4 * c];
        }
        accp = wp[32 * NQCOL].x;
      }
      f16v w0 = wb[0], w1 = wb[1], w2 = wb[2], w3 = wb[3];
      float4 pw = wp[0];
      for (int k4 = 0; k4 < 32; ++k4) {
        f16v nw0, nw1, nw2, nw3; float4 npw;
        if (k4 < 31) {
          const f16v* wn = wb + (k4 + 1) * 176;
          nw0 = wn[0]; nw1 = wn[1]; nw2 = wn[2]; nw3 = wn[3];
          npw = wp[(k4 + 1) * NQCOL];
        }
        float4 xf = xl[(m << 5) + ((k4 + m) & 31)];
        FMA4(w0, 0) FMA4(w1, 4) FMA4(w2, 8) FMA4(w3, 12)
        accp = fmaf(xf.x, pw.x, fmaf(xf.y, pw.y, fmaf(xf.z, pw.z, fmaf(xf.w, pw.w, accp))));
        if (k4 < 31) { w0 = nw0; w1 = nw1; w2 = nw2; w3 = nw3; pw = npw; }
      }
      float bs = accp;
#pragma unroll
      for (int c = 0; c < 16; ++c) bs = fmaf(acc[c], mwr[c], bs);
      if (m < nvalid) beta[(size_t)(n0 + m) * NSTEP + u] = bs * (1.f / 32.f);
    } else {                            // ---- V unit, cols vc0..vc0+15
      int vg = u - 32;
      int vc0 = vg << 4;
      const f16v* wb = (const f16v*)Wq + 136 + (vg << 2);
      float acc[16];
      {
        const f16v* wkb = wb + 32 * 176;
        f16v b0 = wkb[0], b1 = wkb[1], b2 = wkb[2], b3 = wkb[3];
#pragma unroll
        for (int c = 0; c < 4; ++c) {
          acc[c] = b0[4 * c]; acc[4 + c] = b1[4 * c];
          acc[8 + c] = b2[4 * c]; acc[12 + c] = b3[4 * c];
        }
      }
      f16v w0 = wb[0], w1 = wb[1], w2 = wb[2], w3 = wb[3];
      for (int k4 = 0; k4 < 32; ++k4) {
        f16v nw0, nw1, nw2, nw3;
        if (k4 < 31) {
          const f16v* wn = wb + (k4 + 1) * 176;
          nw0 = wn[0]; nw1 = wn[1]; nw2 = wn[2]; nw3 = wn[3];
        }
        float4 xf = xl[(m << 5) + ((k4 + m) & 31)];
        FMA4(w0, 0) FMA4(w1, 4) FMA4(w2, 8) FMA4(w3, 12)
        if (k4 < 31) { w0 = nw0; w1 = nw1; w2 = nw2; w3 = nw3; }
      }
      if (m < nvalid) {
        float* vout = V + (size_t)(n0 + m) * OC + vc0;
#pragma unroll
        for (int q = 0; q < 4; ++q) {
          float4 o;
          o.x = fmaxf(acc[4 * q], 0.f);     o.y = fmaxf(acc[4 * q + 1], 0.f);
          o.z = fmaxf(acc[4 * q + 2], 0.f); o.w = fmaxf(acc[4 * q + 3], 0.f);
          ((float4*)vout)[q] = o;
        }
      }
    }
  }
}

// ---------------- f64 selection scalar (exact top-k path), own kernel
__global__ __launch_bounds__(256) void k_s64(
    const float* __restrict__ x, const float* __restrict__ mw,
    const double* __restrict__ Ud, const double* __restrict__ ubd,
    double* __restrict__ s64) {
  __shared__ float4 xl[64 * 32];
  __shared__ double sdd[64][18];
  int tid = threadIdx.x;
  int n0 = blockIdx.x * 64;
  int nvalid = NN - n0; if (nvalid > 64) nvalid = 64;

  for (int i = tid; i < 64 * 32; i += 256) {
    int mm = i >> 5, k4 = i & 31;
    float4 v = make_float4(0.f, 0.f, 0.f, 0.f);
    if (mm < nvalid) v = ((const float4*)(x + (size_t)(n0 + mm) * IC))[k4];
    xl[(mm << 5) + ((k4 + mm) & 31)] = v;
  }
  __syncthreads();
  int m = tid & 63, j = tid >> 6;
  for (int c = j; c < 17; c += 4) {
    const double* uc = Ud + c * IC;
    double a0 = 0.0, a1 = 0.0, a2 = 0.0, a3 = 0.0;
    for (int k4 = 0; k4 < 32; ++k4) {
      float4 xv = xl[(m << 5) + ((k4 + m) & 31)];
      a0 = fma((double)xv.x, uc[4 * k4],     a0);
      a1 = fma((double)xv.y, uc[4 * k4 + 1], a1);
      a2 = fma((double)xv.z, uc[4 * k4 + 2], a2);
      a3 = fma((double)xv.w, uc[4 * k4 + 3], a3);
    }
    sdd[m][c] = (a0 + a1) + (a2 + a3);
  }
  __syncthreads();
  if (tid < 64 && tid < nvalid) {
    const float* mp = mw + (size_t)(n0 + tid) * 16;
    double ssum = sdd[tid][16] + ubd[16];
#pragma unroll
    for (int c = 0; c < 16; ++c) ssum += (sdd[tid][c] + ubd[c]) * (double)mp[c];
    s64[n0 + tid] = ssum * (1.0 / 1024.0);
  }
}

// -------- edge keys + radix pass 0 fused (hist byte 0 + done-counter pick)
__global__ void k_key(const int* __restrict__ ei, const float* __restrict__ ew,
                      const double* __restrict__ s64,
                      unsigned long long* __restrict__ keys,
                      unsigned* __restrict__ hist, SelState* st) {
  __shared__ unsigned h[256], suf[256];
  __shared__ int last;
  int tid = threadIdx.x;
  h[tid] = 0u;
  if (tid == 0) last = 0;
  __syncthreads();
  for (int e = blockIdx.x * 256 + tid; e < NE; e += gridDim.x * 256) {
    int d = ei[NE + e];
    double v = s64[d] * (double)ew[e];
    unsigned long long u = (unsigned long long)__double_as_longlong(v);
    u = (u & 0x8000000000000000ull) ? ~u : (u | 0x8000000000000000ull);
    keys[e] = u;
    atomicAdd(&h[(unsigned)(u >> 56)], 1u);
  }
  __syncthreads();
  if (h[tid]) atomicAdd(&hist[tid], h[tid]);
  __threadfence();
  __syncthreads();
  if (tid == 0) {
    unsigned old = atomicAdd(&st->done[0], 1u);
    if (old == gridDim.x - 1) last = 1;
  }
  __syncthreads();
  if (!last) return;
  unsigned c = atomicAdd(&hist[tid], 0u);
  suf[tid] = c;
  __syncthreads();
  for (int d = 1; d < 256; d <<= 1) {
    unsigned v = (tid + d < 256) ? suf[tid + d] : 0u;
    __syncthreads();
    suf[tid] += v;
    __syncthreads();
  }
  unsigned r = st->r;
  unsigned exc = suf[tid] - c;
  if (exc < r && exc + c >= r) {
    st->prefix = (unsigned long long)tid;
    st->r = r - exc;
  }
}

// ------------------- radix select pass (hist + parallel suffix-scan pick)
__global__ void k_radix(const unsigned long long* __restrict__ keys,
                        unsigned* __restrict__ hist, SelState* st, int p) {
  __shared__ unsigned h[256], suf[256];
  __shared__ int last;
  int tid = threadIdx.x;
  h[tid] = 0u;
  if (tid == 0) last = 0;
  unsigned long long pref = st->prefix;
  __syncthreads();
  int shift = 56 - 8 * p;
  unsigned* hp = hist + p * 256;
  for (int e = blockIdx.x * 256 + tid; e < NE; e += gridDim.x * 256) {
    unsigned long long k = keys[e];
    if ((k >> (shift + 8)) == pref)
      atomicAdd(&h[(unsigned)((k >> shift) & 255ull)], 1u);
  }
  __syncthreads();
  if (h[tid]) atomicAdd(&hp[tid], h[tid]);
  __threadfence();
  __syncthreads();
  if (tid == 0) {
    unsigned old = atomicAdd(&st->done[p], 1u);
    if (old == gridDim.x - 1) last = 1;
  }
  __syncthreads();
  if (!last) return;
  unsigned c = atomicAdd(&hp[tid], 0u);
  suf[tid] = c;
  __syncthreads();
  for (int d = 1; d < 256; d <<= 1) {
    unsigned v = (tid + d < 256) ? suf[tid + d] : 0u;
    __syncthreads();
    suf[tid] += v;
    __syncthreads();
  }
  unsigned r = st->r;
  unsigned exc = suf[tid] - c;
  if (exc < r && exc + c >= r) {
    st->prefix = (st->prefix << 8) | (unsigned long long)tid;
    st->r = r - exc;
  }
}

// ------------------- collect candidates matching the 16-bit prefix
__global__ void k_cand(const unsigned long long* __restrict__ keys, SelState* st,
                       unsigned long long* __restrict__ candk, int* __restrict__ cande) {
  int e = blockIdx.x * 256 + threadIdx.x;
  if (e >= NE) return;
  unsigned long long k = keys[e];
  if ((unsigned)(k >> 48) == (unsigned)st->prefix) {
    unsigned pos = atomicAdd(&st->tiec, 1u);
    if (pos < CANDCAP) { candk[pos] = k; cande[pos] = e; }
  }
}

// ----------- single block: resolve bytes 2..7 over candidates + tie select
__global__ void k_sel(const unsigned long long* __restrict__ candk,
                      const int* __restrict__ cande, const int* __restrict__ ei,
                      SelState* st, int* __restrict__ sel, unsigned* __restrict__ cnt) {
  __shared__ unsigned h[256], suf[256];
  __shared__ unsigned long long spref;
  __shared__ unsigned sr;
  int tid = threadIdx.x;
  unsigned C = st->tiec; if (C > CANDCAP) C = CANDCAP;
  if (tid == 0) { spref = st->prefix; sr = st->r; }
  __syncthreads();
  for (int p = 2; p < 8; ++p) {
    h[tid] = 0u;
    __syncthreads();
    int shift = 56 - 8 * p;
    unsigned long long pf = spref;
    unsigned r = sr;
    for (unsigned i = tid; i < C; i += 256) {
      unsigned long long k = candk[i];
      if ((k >> (shift + 8)) == pf) atomicAdd(&h[(unsigned)((k >> shift) & 255ull)], 1u);
    }
    __syncthreads();
    suf[tid] = h[tid];
    __syncthreads();
    for (int d = 1; d < 256; d <<= 1) {
      unsigned v = (tid + d < 256) ? suf[tid + d] : 0u;
      __syncthreads();
      suf[tid] += v;
      __syncthreads();
    }
    unsigned exc = suf[tid] - h[tid];
    if (exc < r && exc + h[tid] >= r) {
      spref = (pf << 8) | (unsigned long long)tid;
      sr = r - exc;
    }
    __syncthreads();
  }
  unsigned long long T = spref;
  unsigned needed = sr;
  if (tid == 0) { st->prefix = T; st->r = needed; }
  // ties: take lowest-index `needed` among keys == T
  for (unsigned i = tid; i < C; i += 256) {
    if (candk[i] == T) {
      int e = cande[i];
      unsigned rank = 0;
      for (unsigned q = 0; q < C; ++q)
        rank += (candk[q] == T && cande[q] < e) ? 1u : 0u;
      if (rank < needed) {
        unsigned pos = atomicAdd(&st->selc, 1u);
        if (pos < KSEL) { sel[pos] = e; atomicAdd(&cnt[ei[e]], 1u); }
      }
    }
  }
}

// --------------------------------------------------- selection (> T) + counts
__global__ void k_compact(const unsigned long long* __restrict__ keys,
                          const int* __restrict__ ei, SelState* st,
                          int* __restrict__ sel, unsigned* __restrict__ cnt) {
  int e = blockIdx.x * 256 + threadIdx.x;
  if (e >= NE) return;
  if (keys[e] > st->prefix) {
    unsigned pos = atomicAdd(&st->selc, 1u);
    if (pos < KSEL) { sel[pos] = e; atomicAdd(&cnt[ei[e]], 1u); }
  }
}

// ----------------------------------------------- 3-phase prefix sum -> CSR
__global__ void k_pref1(const unsigned* __restrict__ cnt, unsigned* __restrict__ bsum) {
  __shared__ unsigned sd[256];
  int i = blockIdx.x * 256 + threadIdx.x;
  sd[threadIdx.x] = (i < NN) ? cnt[i] : 0u;
  __syncthreads();
  for (int s = 128; s > 0; s >>= 1) {
    if (threadIdx.x < s) sd[threadIdx.x] += sd[threadIdx.x + s];
    __syncthreads();
  }
  if (threadIdx.x == 0) bsum[blockIdx.x] = sd[0];
}

__global__ void k_pref2(const unsigned* __restrict__ bsum, unsigned* __restrict__ bbase,
                        unsigned* __restrict__ offar) {
  __shared__ unsigned sd[128];
  int tid = threadIdx.x;
  unsigned v = (tid < NB) ? bsum[tid] : 0u;
  sd[tid] = v;
  __syncthreads();
  for (int d = 1; d < 128; d <<= 1) {
    unsigned u = (tid >= d) ? sd[tid - d] : 0u;
    __syncthreads();
    sd[tid] += u;
    __syncthreads();
  }
  if (tid < NB) bbase[tid] = sd[tid] - v;
  if (tid == NB - 1) offar[NN] = sd[tid];
}

__global__ void k_pref3(const unsigned* __restrict__ cnt, const unsigned* __restrict__ bbase,
                        unsigned* __restrict__ offar, unsigned* __restrict__ cursor) {
  __shared__ unsigned sd[256];
  int tid = threadIdx.x;
  int i = blockIdx.x * 256 + tid;
  unsigned v = (i < NN) ? cnt[i] : 0u;
  sd[tid] = v;
  __syncthreads();
  for (int d = 1; d < 256; d <<= 1) {
    unsigned u = (tid >= d) ? sd[tid - d] : 0u;
    __syncthreads();
    sd[tid] += u;
    __syncthreads();
  }
  if (i < NN) {
    unsigned excl = bbase[blockIdx.x] + sd[tid] - v;
    offar[i] = excl;
    cursor[i] = excl;
  }
}

__global__ void k_scatter(const int* __restrict__ sel, const int* __restrict__ ei,
                          unsigned* __restrict__ cursor, int* __restrict__ csr) {
  int i = blockIdx.x * 256 + threadIdx.x;
  if (i >= KSEL) return;
  int e = sel[i];
  unsigned pos = atomicAdd(&cursor[ei[e]], 1u);
  if (pos < KSEL) csr[pos] = e;
}

// --------- per-node online softmax + weighted scatter (single batched pass)
__global__ __launch_bounds__(128) void k_out(
    const int* __restrict__ ei, const float* __restrict__ ew,
    const float* __restrict__ beta, const float* __restrict__ V,
    const unsigned* __restrict__ offar, const int* __restrict__ csr,
    float* __restrict__ out) {
  __shared__ float B[32][NSTEP];       // staged beta*ew, overwritten with g
  __shared__ float m[NSTEP], den[NSTEP], scale[NSTEP];
  __shared__ int dl[32];
  __shared__ float ewl[32];
  int n = blockIdx.x, tid = threadIdx.x;
  unsigned beg = offar[n], end = offar[n + 1];
  if (end > (unsigned)KSEL) end = KSEL;
  if (beg > end) beg = end;
  if (tid < NSTEP) { m[tid] = -INFINITY; den[tid] = 0.f; }
  float acc = 0.f;
  int c = tid, tq = tid >> 2;
  __syncthreads();

  for (unsigned cb = beg; cb < end; cb += 32u) {
    unsigned ce = end - cb; if (ce > 32u) ce = 32u;
    if (tid < (int)ce) {
      int e = csr[cb + tid];
      dl[tid] = ei[NE + e];
      ewl[tid] = ew[e];
    }
    __syncthreads();
    // stage beta rows * ew (batched coalesced gather)
    for (int idx = tid; idx < (int)ce * NSTEP; idx += 128) {
      int el = idx >> 5, t = idx & 31;
      B[el][t] = beta[(size_t)dl[el] * NSTEP + t] * ewl[el];
    }
    __syncthreads();
    // per-t: chunk max, rescale factor, g in place, den update
    if (tid < NSTEP) {
      int t = tid;
      float mc = -INFINITY;
      for (int el = 0; el < (int)ce; ++el) mc = fmaxf(mc, B[el][t]);
      float mnew = fmaxf(m[t], mc);
      float sc = expf(m[t] - mnew);       // 0 when m was -inf
      float s = 0.f;
      for (int el = 0; el < (int)ce; ++el) {
        float g = expf(B[el][t] - mnew);
        B[el][t] = g;
        s += g;
      }
      den[t] = den[t] * sc + s;
      m[t] = mnew;
      scale[t] = sc;
    }
    __syncthreads();
    acc *= scale[tq];
    for (int el = 0; el < (int)ce; ++el)
      acc += V[(size_t)dl[el] * OC + c] * B[el][tq];
    __syncthreads();
  }
  float d = den[tq];
  out[(size_t)n * OC + c] = (d > 0.f) ? acc / d : 0.f;
}

// --------------------------------------------------------------------- host
extern "C" void kernel_launch(void* const* d_in, const int* in_sizes, int n_in,
                              void* d_out, int out_size, void* d_ws, size_t ws_size,
                              hipStream_t stream) {
  const float* x     = (const float*)d_in[0];
  const float* p_t   = (const float*)d_in[1];
  const int*   ei    = (const int*)d_in[2];
  const float* ew    = (const float*)d_in[3];
  const float* lin_w = (const float*)d_in[4];
  const float* lin_b = (const float*)d_in[5];
  const float* inc_w = (const float*)d_in[6];
  const float* inc_b = (const float*)d_in[7];
  const float* mw    = (const float*)d_in[8];
  float* out = (float*)d_out;

  char* w = (char*)d_ws;
  size_t off = 0;
  auto alloc = [&](size_t b) -> void* {
    void* p = w + off;
    off += (b + 511) & ~(size_t)511;
    return p;
  };
  float*  Wq    = (float*)alloc((size_t)33 * NQCOL * 4 * 4);
  double* Ud    = (double*)alloc((size_t)17 * IC * 8);
  double* ubd   = (double*)alloc(17 * 8);
  float*  beta  = (float*)alloc((size_t)NN * NSTEP * 4);
  double* s64   = (double*)alloc((size_t)NN * 8);
  float*  V     = (float*)alloc((size_t)NN * OC * 4);
  unsigned long long* keys  = (unsigned long long*)alloc((size_t)NE * 8);
  unsigned long long* candk = (unsigned long long*)alloc((size_t)CANDCAP * 8);
  int*      cande  = (int*)alloc((size_t)CANDCAP * 4);
  int*      sel    = (int*)alloc((size_t)KSEL * 4);
  unsigned* cnt    = (unsigned*)alloc((size_t)NN * 4);
  unsigned* offar  = (unsigned*)alloc((size_t)(NN + 1) * 4);
  unsigned* cursor = (unsigned*)alloc((size_t)NN * 4);
  int*      csr    = (int*)alloc((size_t)KSEL * 4);
  unsigned* hist   = (unsigned*)alloc(512 * 4);
  unsigned* bsum   = (unsigned*)alloc(NB * 4);
  unsigned* bbase  = (unsigned*)alloc(NB * 4);
  SelState* st     = (SelState*)alloc(sizeof(SelState));
  if (off > ws_size) return;

  int init_threads = 33 * NQCOL + 17 * IC + 17 + NN + 512 + 1;
  k_init<<<(init_threads + 255) / 256, 256, 0, stream>>>(p_t, lin_w, lin_b, inc_w, inc_b,
                                                         Wq, Ud, ubd, cnt, hist, st);
  k_node<<<dim3((NN + 63) / 64, 5), 256, 0, stream>>>(x, mw, Wq, beta, V);
  k_s64<<<(NN + 63) / 64, 256, 0, stream>>>(x, mw, Ud, ubd, s64);
  k_key<<<256, 256, 0, stream>>>(ei, ew, s64, keys, hist, st);
  k_radix<<<256, 256, 0, stream>>>(keys, hist, st, 1);
  k_cand<<<(NE + 255) / 256, 256, 0, stream>>>(keys, st, candk, cande);
  k_sel<<<1, 256, 0, stream>>>(candk, cande, ei, st, sel, cnt);
  k_compact<<<(NE + 255) / 256, 256, 0, stream>>>(keys, ei, st, sel, cnt);
  k_pref1<<<NB, 256, 0, stream>>>(cnt, bsum);
  k_pref2<<<1, 128, 0, stream>>>(bsum, bbase, offar);
  k_pref3<<<NB, 256, 0, stream>>>(cnt, bbase, offar, cursor);
  k_scatter<<<(KSEL + 255) / 256, 256, 0, stream>>>(sel, ei, cursor, csr);
  k_out<<<NN, 128, 0, stream>>>(ei, ew, beta, V, offar, csr, out);
}